// Round 9
// baseline (286.073 us; speedup 1.0000x reference)
//
#include <hip/hip_runtime.h>
#include <hip/hip_bf16.h>
#include <cstdint>
#include <cstddef>

// Problem constants
#define NT 8192
#define DD 512
#define HH 2048
#define NE 4
#define BK 64          // K-tile; 8 chunks of 16B per row = full 32-bank coverage (0 conflicts, R5/R8)
#define RP 136         // ffn2 repack row stride (elems)
#define RP1 264        // ffn1 repack row stride (256-wide tile)
#define MAXT128 131    // sum_e ceil(cnt_e/128) <= 128 + 3

typedef short short8 __attribute__((ext_vector_type(8)));
typedef float floatx4 __attribute__((ext_vector_type(4)));

static __device__ __forceinline__ unsigned short f2bf(float f) {
    union { float f; uint32_t u; } v; v.f = f;
    uint32_t u = v.u;
    u += 0x7FFFu + ((u >> 16) & 1u);   // round-to-nearest-even
    return (unsigned short)(u >> 16);
}
static __device__ __forceinline__ float bf2f(unsigned short u) {
    union { uint32_t u; float f; } v; v.u = ((uint32_t)u) << 16; return v.f;
}

// async global->LDS, 16B per lane. LDS dest = wave-uniform base + lane*16.
static __device__ __forceinline__ void gld_lds16(const unsigned short* g, unsigned short* l) {
    __builtin_amdgcn_global_load_lds(
        (const __attribute__((address_space(1))) void*)g,
        (__attribute__((address_space(3))) void*)l, 16, 0, 0);
}

// ------------- merged prep: weight transpose+cast (blocks 0..8191) + gate (blocks 8192..) -------------
__global__ __launch_bounds__(256) void k_prep(
    const float* __restrict__ w1, unsigned short* __restrict__ w1t,
    const float* __restrict__ w2, unsigned short* __restrict__ w2t,
    const float* __restrict__ h, const float* __restrict__ wg,
    int* __restrict__ sel, float* __restrict__ gv, unsigned short* __restrict__ hb) {
    if (blockIdx.x < 8192) {
        int z = blockIdx.x >> 10;
        int rem = blockIdx.x & 1023;
        int bx = rem & 63, by = rem >> 6;
        const float* in; unsigned short* out; int R, C, r0, c0;
        if (z < 4) {
            in = w1 + (size_t)z * DD * HH; out = w1t + (size_t)z * DD * HH;
            R = DD; C = HH; r0 = by * 32; c0 = bx * 32;
        } else {
            in = w2 + (size_t)(z - 4) * HH * DD; out = w2t + (size_t)(z - 4) * HH * DD;
            R = HH; C = DD; r0 = bx * 32; c0 = by * 32;
        }
        __shared__ float tile[32][33];
        int tx = threadIdx.x & 31, ty = threadIdx.x >> 5;
#pragma unroll
        for (int it = 0; it < 4; it++) {
            int r = ty + it * 8;
            tile[r][tx] = in[(size_t)(r0 + r) * C + c0 + tx];
        }
        __syncthreads();
#pragma unroll
        for (int it = 0; it < 4; it++) {
            int r = ty + it * 8;
            out[(size_t)(c0 + r) * R + r0 + tx] = f2bf(tile[tx][r]);
        }
        return;
    }
    // ---- gating: fp32 logits, exact top-2, softmax over top-2, fused h->bf16 cast ----
    int wid = threadIdx.x >> 6, lane = threadIdx.x & 63;
    int n = (blockIdx.x - 8192) * 4 + wid;
    const float* hr = h + (size_t)n * DD;
    int d0 = lane * 8;
    float hv[8];
    *(float4*)(hv)     = *(const float4*)(hr + d0);
    *(float4*)(hv + 4) = *(const float4*)(hr + d0 + 4);
    unsigned short tmp[8];
#pragma unroll
    for (int j = 0; j < 8; j++) tmp[j] = f2bf(hv[j]);
    *(uint4*)(hb + (size_t)n * DD + d0) = *(const uint4*)tmp;

    float a0 = 0.f, a1 = 0.f, a2 = 0.f, a3 = 0.f;
#pragma unroll
    for (int j = 0; j < 8; j++) {
        float4 w = *(const float4*)(wg + (size_t)(d0 + j) * 4);
        a0 += hv[j] * w.x; a1 += hv[j] * w.y; a2 += hv[j] * w.z; a3 += hv[j] * w.w;
    }
#pragma unroll
    for (int off = 32; off; off >>= 1) {
        a0 += __shfl_xor(a0, off);
        a1 += __shfl_xor(a1, off);
        a2 += __shfl_xor(a2, off);
        a3 += __shfl_xor(a3, off);
    }
    if (lane == 0) {
        float v[4] = {a0, a1, a2, a3};
        int e0 = 0; float b = v[0];
#pragma unroll
        for (int e = 1; e < 4; e++) if (v[e] > b) { b = v[e]; e0 = e; }
        int e1 = -1; float b2 = -1e30f;
#pragma unroll
        for (int e = 0; e < 4; e++) if (e != e0 && v[e] > b2) { b2 = v[e]; e1 = e; }
        float x = expf(b2 - b);
        float s = 1.f + x;
        sel[2 * n] = e0; sel[2 * n + 1] = e1;
        gv[2 * n] = 1.f / s; gv[2 * n + 1] = x / s;
    }
}

// ---------------- single-block scan (1024 thr, wave-level shfl scans, 2 barriers) ----------------
// ctl: [8..11]=expert base, [12]=total, [13]=n128 tiles
__global__ __launch_bounds__(1024) void k_scan(const int* __restrict__ sel, const float* __restrict__ gv,
                                               int* __restrict__ ctl, int* __restrict__ rtok,
                                               float* __restrict__ rgte, int* __restrict__ slotof,
                                               int* __restrict__ tiles) {
    __shared__ int wtot[4][16];
    __shared__ int wbase[4][16];
    __shared__ int ebase[4];
    int t = threadIdx.x, w = t >> 6, lane = t & 63;
    int c[4] = {0, 0, 0, 0};
    int selloc[16];
    const int4* s4 = (const int4*)sel;
#pragma unroll
    for (int i = 0; i < 4; i++) {
        int4 v = s4[t * 4 + i];
        selloc[i * 4 + 0] = v.x; c[v.x]++;
        selloc[i * 4 + 1] = v.y; c[v.y]++;
        selloc[i * 4 + 2] = v.z; c[v.z]++;
        selloc[i * 4 + 3] = v.w; c[v.w]++;
    }
    int inc[4] = {c[0], c[1], c[2], c[3]};
#pragma unroll
    for (int off = 1; off < 64; off <<= 1) {
#pragma unroll
        for (int e = 0; e < 4; e++) {
            int v = __shfl_up(inc[e], off);
            if (lane >= off) inc[e] += v;
        }
    }
    if (lane == 63)
#pragma unroll
        for (int e = 0; e < 4; e++) wtot[e][w] = inc[e];
    __syncthreads();
    if (t == 0) {
        int o = 0, nt = 0;
#pragma unroll
        for (int e = 0; e < 4; e++) {
            int s = 0;
            for (int ww = 0; ww < 16; ww++) { wbase[e][ww] = s; s += wtot[e][ww]; }
            ebase[e] = o; ctl[8 + e] = o;
            for (int m0 = 0; m0 < s; m0 += 128) tiles[nt++] = (e << 16) | m0;
            o += s;
        }
        ctl[12] = o; ctl[13] = nt;
    }
    __syncthreads();
    int pos[4];
#pragma unroll
    for (int e = 0; e < 4; e++) pos[e] = ebase[e] + wbase[e][w] + inc[e] - c[e];  // exclusive
#pragma unroll
    for (int i = 0; i < 16; i++) {
        int idx = t * 16 + i;          // = 2*n + k
        int e = selloc[i];
        int s = pos[e]++;
        rtok[s] = idx >> 1;
        rgte[s] = gv[idx];
        slotof[idx] = s;
    }
}

// ---- grouped GEMM 1 (512 thr, 128m x 256n, wave-tile 64x64): mid = relu(gather(h)@w1[e]+b1[e]) ----
__global__ __launch_bounds__(512) void k_ffn1(
    const unsigned short* __restrict__ hb, const unsigned short* __restrict__ w1t,
    const float* __restrict__ b1, const int* __restrict__ ctl, const int* __restrict__ tiles,
    const int* __restrict__ rtok, unsigned short* __restrict__ mid) {
    if ((int)blockIdx.y >= ctl[13]) return;
    int tv = tiles[blockIdx.y];
    int e = tv >> 16, m0 = tv & 0xFFFF;
    int base = ctl[8 + e];
    int cnt = ctl[9 + e] - base;
    int n0 = blockIdx.x * 256;

    // staging: A[128][64] (8192 el) + B[256][64] (16384 el) = 24576 el; repack 128*264 = 33792 el
    __shared__ unsigned short smem[33792];
    __shared__ int toks[128];
    unsigned short* As = smem;
    unsigned short* Bs = smem + 8192;

    int t = threadIdx.x;
    if (t < 128) {
        int r = m0 + t; if (r >= cnt) r = cnt - 1;
        toks[t] = rtok[base + r];
    }
    __syncthreads();

    const unsigned short* wB = w1t + (size_t)e * HH * DD;
    int w = t >> 6, lane = t & 63;
    int wm = (w & 1) * 64, wn = (w >> 1) * 64;   // wave tile 64x64; 2x4 wave grid
    int lrow = lane & 15, quad = lane >> 4;

    // staging: wave w stages A rows [w*16,w*16+16) (2 calls) and B rows [w*32,w*32+32) (4 calls).
    // swizzle: LDS slot (row, p) holds global chunk (p - row) & 7.
    const unsigned short* gA[2]; unsigned short* lA[2];
    const unsigned short* gB[4]; unsigned short* lB[4];
    int srow8 = lane >> 3, sch = lane & 7;
#pragma unroll
    for (int c = 0; c < 2; c++) {
        int row = w * 16 + c * 8 + srow8;
        int cg = (sch - row) & 7;
        gA[c] = hb + (size_t)toks[row] * DD + cg * 8;
        lA[c] = As + row * BK + sch * 8;
    }
#pragma unroll
    for (int c = 0; c < 4; c++) {
        int row = w * 32 + c * 8 + srow8;
        int cg = (sch - row) & 7;
        gB[c] = wB + (size_t)(n0 + row) * DD + cg * 8;
        lB[c] = Bs + row * BK + sch * 8;
    }

    floatx4 acc[4][4];
#pragma unroll
    for (int i = 0; i < 4; i++)
#pragma unroll
        for (int j = 0; j < 4; j++) acc[i][j] = (floatx4)0.f;

    for (int kk = 0; kk < DD; kk += BK) {
#pragma unroll
        for (int c = 0; c < 2; c++) gld_lds16(gA[c] + kk, lA[c]);
#pragma unroll
        for (int c = 0; c < 4; c++) gld_lds16(gB[c] + kk, lB[c]);
        __syncthreads();
#pragma unroll
        for (int ks = 0; ks < 2; ks++) {
            short8 af[4], bf[4];
#pragma unroll
            for (int i = 0; i < 4; i++) {
                int row = wm + 16 * i + lrow;
                af[i] = *(const short8*)&As[row * BK + (((ks << 2) + quad + row) & 7) * 8];
            }
#pragma unroll
            for (int j = 0; j < 4; j++) {
                int row = wn + 16 * j + lrow;
                bf[j] = *(const short8*)&Bs[row * BK + (((ks << 2) + quad + row) & 7) * 8];
            }
#pragma unroll
            for (int i = 0; i < 4; i++)
#pragma unroll
                for (int j = 0; j < 4; j++)
                    acc[i][j] = __builtin_amdgcn_mfma_f32_16x16x32_bf16(af[i], bf[j], acc[i][j], 0, 0, 0);
        }
        __syncthreads();
    }

    // epilogue: bias + relu -> repack (aliases dead staging) -> coalesced stores
    float bias[4];
#pragma unroll
    for (int j = 0; j < 4; j++) bias[j] = b1[e * HH + n0 + wn + 16 * j + lrow];
#pragma unroll
    for (int j = 0; j < 4; j++) {
        int col = wn + 16 * j + lrow;
#pragma unroll
        for (int i = 0; i < 4; i++) {
#pragma unroll
            for (int r = 0; r < 4; r++) {
                int m = wm + 16 * i + quad * 4 + r;
                float v = acc[i][j][r] + bias[j];
                v = v > 0.f ? v : 0.f;
                smem[m * RP1 + col] = f2bf(v);
            }
        }
    }
    __syncthreads();
    {
        int row = t >> 2, q = t & 3;   // 128 rows x 4 chunks of 64 elems
        if (m0 + row < cnt) {
            unsigned short* dst = mid + (size_t)(base + m0 + row) * HH + n0 + q * 64;
            const unsigned short* src = smem + row * RP1 + q * 64;
#pragma unroll
            for (int it = 0; it < 8; it++)
                *(uint4*)(dst + it * 8) = *(const uint4*)(src + it * 8);
        }
    }
}

// ---- grouped GEMM 2 (256 thr, 128x128, wave-tile 64x64, m97-style): ybuf[slot]=gate*(mid@w2[e]+b2[e]) ----
__global__ __launch_bounds__(256) void k_ffn2(
    const unsigned short* __restrict__ mid, const unsigned short* __restrict__ w2t,
    const float* __restrict__ b2, const int* __restrict__ ctl, const int* __restrict__ tiles,
    const float* __restrict__ rgte, unsigned short* __restrict__ ybuf) {
    if ((int)blockIdx.y >= ctl[13]) return;
    int tv = tiles[blockIdx.y];
    int e = tv >> 16, m0 = tv & 0xFFFF;
    int base = ctl[8 + e];
    int cnt = ctl[9 + e] - base;
    int n0 = blockIdx.x * 128;

    __shared__ unsigned short smem[17408];   // staging 2*128*64=16384 el; repack 128*136=17408 el
    __shared__ float gts[128];
    unsigned short* As = smem;
    unsigned short* Bs = smem + 8192;

    int t = threadIdx.x;
    if (t < 128) {
        int r = m0 + t; if (r >= cnt) r = cnt - 1;
        gts[t] = rgte[base + r];
    }
    __syncthreads();

    const unsigned short* wB = w2t + (size_t)e * DD * HH;
    int w = t >> 6, lane = t & 63;
    int wm = (w & 1) * 64, wn = (w >> 1) * 64;   // wave tile 64x64; 2x2 wave grid
    int lrow = lane & 15, quad = lane >> 4;

    // staging: wave w stages A rows [w*32,w*32+32) and B rows [w*32,w*32+32); 4 calls each.
    const unsigned short* gA[4]; unsigned short* lA[4];
    const unsigned short* gB[4]; unsigned short* lB[4];
    int srow8 = lane >> 3, sch = lane & 7;
#pragma unroll
    for (int c = 0; c < 4; c++) {
        int row = w * 32 + c * 8 + srow8;
        int cg = (sch - row) & 7;
        int ra = m0 + row; if (ra >= cnt) ra = cnt - 1;
        gA[c] = mid + (size_t)(base + ra) * HH + cg * 8;
        lA[c] = As + row * BK + sch * 8;
        gB[c] = wB + (size_t)(n0 + row) * HH + cg * 8;
        lB[c] = Bs + row * BK + sch * 8;
    }

    floatx4 acc[4][4];
#pragma unroll
    for (int i = 0; i < 4; i++)
#pragma unroll
        for (int j = 0; j < 4; j++) acc[i][j] = (floatx4)0.f;

    for (int kk = 0; kk < HH; kk += BK) {
#pragma unroll
        for (int c = 0; c < 4; c++) {
            gld_lds16(gA[c] + kk, lA[c]);
            gld_lds16(gB[c] + kk, lB[c]);
        }
        __syncthreads();
#pragma unroll
        for (int ks = 0; ks < 2; ks++) {
            short8 af[4], bf[4];
#pragma unroll
            for (int i = 0; i < 4; i++) {
                int row = wm + 16 * i + lrow;
                af[i] = *(const short8*)&As[row * BK + (((ks << 2) + quad + row) & 7) * 8];
            }
#pragma unroll
            for (int j = 0; j < 4; j++) {
                int row = wn + 16 * j + lrow;
                bf[j] = *(const short8*)&Bs[row * BK + (((ks << 2) + quad + row) & 7) * 8];
            }
#pragma unroll
            for (int i = 0; i < 4; i++)
#pragma unroll
                for (int j = 0; j < 4; j++)
                    acc[i][j] = __builtin_amdgcn_mfma_f32_16x16x32_bf16(af[i], bf[j], acc[i][j], 0, 0, 0);
        }
        __syncthreads();
    }

    // epilogue: bias + gate-scale -> repack -> coalesced stores
    float b2v[4];
#pragma unroll
    for (int j = 0; j < 4; j++) b2v[j] = b2[e * DD + n0 + wn + 16 * j + lrow];
#pragma unroll
    for (int j = 0; j < 4; j++) {
        int col = wn + 16 * j + lrow;
#pragma unroll
        for (int i = 0; i < 4; i++) {
#pragma unroll
            for (int r = 0; r < 4; r++) {
                int m = wm + 16 * i + quad * 4 + r;
                float v = (acc[i][j][r] + b2v[j]) * gts[m];
                smem[m * RP + col] = f2bf(v);
            }
        }
    }
    __syncthreads();
    {
        int row = t >> 1, half = t & 1;   // 128 rows x 2 chunks of 64 elems
        if (m0 + row < cnt) {
            unsigned short* dst = ybuf + (size_t)(base + m0 + row) * DD + n0 + half * 64;
            const unsigned short* src = smem + row * RP + half * 64;
#pragma unroll
            for (int it = 0; it < 8; it++)
                *(uint4*)(dst + it * 8) = *(const uint4*)(src + it * 8);
        }
    }
}

// ---------------- combine: out[n] = ybuf[slot(n,0)] + ybuf[slot(n,1)] ----------------
__global__ void k_combine(const unsigned short* __restrict__ ybuf, const int* __restrict__ slotof,
                          float* __restrict__ out) {
    int n = blockIdx.x * 2 + (threadIdx.x >> 7);
    int c = (threadIdx.x & 127) * 4;
    int sA = slotof[2 * n], sB = slotof[2 * n + 1];
    ushort4 a = *(const ushort4*)(ybuf + (size_t)sA * DD + c);
    ushort4 b = *(const ushort4*)(ybuf + (size_t)sB * DD + c);
    float4 o;
    o.x = bf2f(a.x) + bf2f(b.x);
    o.y = bf2f(a.y) + bf2f(b.y);
    o.z = bf2f(a.z) + bf2f(b.z);
    o.w = bf2f(a.w) + bf2f(b.w);
    *(float4*)(out + (size_t)n * DD + c) = o;
}

extern "C" void kernel_launch(void* const* d_in, const int* in_sizes, int n_in,
                              void* d_out, int out_size, void* d_ws, size_t ws_size,
                              hipStream_t stream) {
    const float* h  = (const float*)d_in[0];
    const float* wg = (const float*)d_in[1];
    const float* w1 = (const float*)d_in[2];
    const float* b1 = (const float*)d_in[3];
    const float* w2 = (const float*)d_in[4];
    const float* b2 = (const float*)d_in[5];
    float* out = (float*)d_out;

    char* ws = (char*)d_ws;
    size_t off = 0;
    auto alloc = [&](size_t bytes) -> void* {
        void* p = ws + off;
        off += (bytes + 255) & ~(size_t)255;
        return p;
    };
    unsigned short* hb  = (unsigned short*)alloc((size_t)NT * DD * 2);        // dead after ffn1
    unsigned short* w1t = (unsigned short*)alloc((size_t)NE * HH * DD * 2);   // dead after ffn1
    unsigned short* w2t = (unsigned short*)alloc((size_t)NE * DD * HH * 2);
    int*   sel    = (int*)alloc((size_t)NT * 2 * 4);
    float* gv     = (float*)alloc((size_t)NT * 2 * 4);
    int*   ctl    = (int*)alloc(256);
    int*   tiles  = (int*)alloc(1024);
    int*   rtok   = (int*)alloc((size_t)NT * 2 * 4);
    float* rgte   = (float*)alloc((size_t)NT * 2 * 4);
    int*   slotof = (int*)alloc((size_t)NT * 2 * 4);
    unsigned short* mid = (unsigned short*)alloc((size_t)NT * 2 * HH * 2);
    // ybuf [NT*2][DD] bf16 (16.7 MB) aliases hb+w1t (16.7 MB), both dead before ffn2 runs
    unsigned short* ybuf = (unsigned short*)ws;

    k_prep<<<dim3(8192 + NT / 4), 256, 0, stream>>>(w1, w1t, w2, w2t, h, wg, sel, gv, hb);
    k_scan<<<1, 1024, 0, stream>>>(sel, gv, ctl, rtok, rgte, slotof, tiles);
    k_ffn1<<<dim3(HH / 256, MAXT128), 512, 0, stream>>>(hb, w1t, b1, ctl, tiles, rtok, mid);
    k_ffn2<<<dim3(DD / 128, MAXT128), 256, 0, stream>>>(mid, w2t, b2, ctl, tiles, rgte, ybuf);
    k_combine<<<dim3(NT / 2), 256, 0, stream>>>(ybuf, slotof, out);
}

// Round 10
// 261.646 us; speedup vs baseline: 1.0934x; 1.0934x over previous
//
#include <hip/hip_runtime.h>
#include <hip/hip_bf16.h>
#include <cstdint>
#include <cstddef>

// Problem constants
#define NT 8192
#define DD 512
#define HH 2048
#define NE 4
#define BK 64          // K-tile; 8 chunks of 16B per row = full 32-bank coverage (0 conflicts R5/R8)
#define RP 136         // repack row stride (elems), proven ~0 conflicts
#define BUFE 16384     // elems per staging buffer (A 128x64 + B 128x64 = 32 KB)
#define MAXT128 131    // sum_e ceil(cnt_e/128) <= 128 + 3
#define FFN1_GRID 2176 // 17 mt-groups x 8 xcd x 16 n-tiles
#define FFN2_GRID 544  // 17 mt-groups x 8 xcd x 4 n-tiles

typedef short short8 __attribute__((ext_vector_type(8)));
typedef float floatx4 __attribute__((ext_vector_type(4)));

static __device__ __forceinline__ unsigned short f2bf(float f) {
    union { float f; uint32_t u; } v; v.f = f;
    uint32_t u = v.u;
    u += 0x7FFFu + ((u >> 16) & 1u);   // round-to-nearest-even
    return (unsigned short)(u >> 16);
}
static __device__ __forceinline__ float bf2f(unsigned short u) {
    union { uint32_t u; float f; } v; v.u = ((uint32_t)u) << 16; return v.f;
}

// async global->LDS, 16B per lane. LDS dest = wave-uniform base + lane*16.
static __device__ __forceinline__ void gld_lds16(const unsigned short* g, unsigned short* l) {
    __builtin_amdgcn_global_load_lds(
        (const __attribute__((address_space(1))) void*)g,
        (__attribute__((address_space(3))) void*)l, 16, 0, 0);
}

// ------------- merged prep (512 thr): weight transpose+cast (blocks 0..4095) + gate (4096..) -------------
// transpose tile: 64 input rows x 32 input cols -> output stores are 64 bf16 = 128B full lines
__global__ __launch_bounds__(512) void k_prep(
    const float* __restrict__ w1, unsigned short* __restrict__ w1t,
    const float* __restrict__ w2, unsigned short* __restrict__ w2t,
    const float* __restrict__ h, const float* __restrict__ wg,
    int* __restrict__ sel, float* __restrict__ gv, unsigned short* __restrict__ hb) {
    int t = threadIdx.x;
    if (blockIdx.x < 4096) {
        int z = blockIdx.x >> 9;            // 512 blocks per expert-matrix
        int rem = blockIdx.x & 511;
        const float* in; unsigned short* out; int R, C, by, bx;
        if (z < 4) {
            in = w1 + (size_t)z * DD * HH; out = w1t + (size_t)z * DD * HH;
            R = DD; C = HH; by = rem >> 6; bx = rem & 63;      // 8 x 64
        } else {
            in = w2 + (size_t)(z - 4) * HH * DD; out = w2t + (size_t)(z - 4) * HH * DD;
            R = HH; C = DD; by = rem >> 4; bx = rem & 15;      // 32 x 16
        }
        int r0 = by * 64, c0 = bx * 32;
        __shared__ float tile[64][33];
        int tx = t & 31, ty = t >> 5;       // 32 x 16
#pragma unroll
        for (int it = 0; it < 4; it++) {
            int r = ty + it * 16;
            tile[r][tx] = in[(size_t)(r0 + r) * C + c0 + tx];
        }
        __syncthreads();
        int c8 = t >> 6, tx64 = t & 63;     // 8 out-cols per pass x 64-wide rows
#pragma unroll
        for (int it = 0; it < 4; it++) {
            int c = c8 + it * 8;
            out[(size_t)(c0 + c) * R + r0 + tx64] = f2bf(tile[tx64][c]);
        }
        return;
    }
    // ---- gating: fp32 logits, exact top-2, softmax over top-2, fused h->bf16 cast (8 tokens/block) ----
    int wid = t >> 6, lane = t & 63;
    int n = (blockIdx.x - 4096) * 8 + wid;
    const float* hr = h + (size_t)n * DD;
    int d0 = lane * 8;
    float hv[8];
    *(float4*)(hv)     = *(const float4*)(hr + d0);
    *(float4*)(hv + 4) = *(const float4*)(hr + d0 + 4);
    unsigned short tmp[8];
#pragma unroll
    for (int j = 0; j < 8; j++) tmp[j] = f2bf(hv[j]);
    *(uint4*)(hb + (size_t)n * DD + d0) = *(const uint4*)tmp;

    float a0 = 0.f, a1 = 0.f, a2 = 0.f, a3 = 0.f;
#pragma unroll
    for (int j = 0; j < 8; j++) {
        float4 w = *(const float4*)(wg + (size_t)(d0 + j) * 4);
        a0 += hv[j] * w.x; a1 += hv[j] * w.y; a2 += hv[j] * w.z; a3 += hv[j] * w.w;
    }
#pragma unroll
    for (int off = 32; off; off >>= 1) {
        a0 += __shfl_xor(a0, off);
        a1 += __shfl_xor(a1, off);
        a2 += __shfl_xor(a2, off);
        a3 += __shfl_xor(a3, off);
    }
    if (lane == 0) {
        float v[4] = {a0, a1, a2, a3};
        int e0 = 0; float b = v[0];
#pragma unroll
        for (int e = 1; e < 4; e++) if (v[e] > b) { b = v[e]; e0 = e; }
        int e1 = -1; float b2 = -1e30f;
#pragma unroll
        for (int e = 0; e < 4; e++) if (e != e0 && v[e] > b2) { b2 = v[e]; e1 = e; }
        float x = expf(b2 - b);
        float s = 1.f + x;
        sel[2 * n] = e0; sel[2 * n + 1] = e1;
        gv[2 * n] = 1.f / s; gv[2 * n + 1] = x / s;
    }
}

// ---------------- single-block scan (1024 thr, wave-level shfl scans, 2 barriers) ----------------
// ctl: [8..11]=expert base, [12]=total, [13]=n128 tiles
__global__ __launch_bounds__(1024) void k_scan(const int* __restrict__ sel, const float* __restrict__ gv,
                                               int* __restrict__ ctl, int* __restrict__ rtok,
                                               float* __restrict__ rgte, int* __restrict__ slotof,
                                               int* __restrict__ tiles) {
    __shared__ int wtot[4][16];
    __shared__ int wbase[4][16];
    __shared__ int ebase[4];
    int t = threadIdx.x, w = t >> 6, lane = t & 63;
    int c[4] = {0, 0, 0, 0};
    int selloc[16];
    const int4* s4 = (const int4*)sel;
#pragma unroll
    for (int i = 0; i < 4; i++) {
        int4 v = s4[t * 4 + i];
        selloc[i * 4 + 0] = v.x; c[v.x]++;
        selloc[i * 4 + 1] = v.y; c[v.y]++;
        selloc[i * 4 + 2] = v.z; c[v.z]++;
        selloc[i * 4 + 3] = v.w; c[v.w]++;
    }
    int inc[4] = {c[0], c[1], c[2], c[3]};
#pragma unroll
    for (int off = 1; off < 64; off <<= 1) {
#pragma unroll
        for (int e = 0; e < 4; e++) {
            int v = __shfl_up(inc[e], off);
            if (lane >= off) inc[e] += v;
        }
    }
    if (lane == 63)
#pragma unroll
        for (int e = 0; e < 4; e++) wtot[e][w] = inc[e];
    __syncthreads();
    if (t == 0) {
        int o = 0, nt = 0;
#pragma unroll
        for (int e = 0; e < 4; e++) {
            int s = 0;
            for (int ww = 0; ww < 16; ww++) { wbase[e][ww] = s; s += wtot[e][ww]; }
            ebase[e] = o; ctl[8 + e] = o;
            for (int m0 = 0; m0 < s; m0 += 128) tiles[nt++] = (e << 16) | m0;
            o += s;
        }
        ctl[12] = o; ctl[13] = nt;
    }
    __syncthreads();
    int pos[4];
#pragma unroll
    for (int e = 0; e < 4; e++) pos[e] = ebase[e] + wbase[e][w] + inc[e] - c[e];  // exclusive
#pragma unroll
    for (int i = 0; i < 16; i++) {
        int idx = t * 16 + i;          // = 2*n + k
        int e = selloc[i];
        int s = pos[e]++;
        rtok[s] = idx >> 1;
        rgte[s] = gv[idx];
        slotof[idx] = s;
    }
}

// ---- grouped GEMM 1 (512 thr, 128x128, dbuf, XCD-quartet swizzle): mid = relu(gather(h)@w1[e]+b1[e]) ----
__global__ __launch_bounds__(512) void k_ffn1(
    const unsigned short* __restrict__ hb, const unsigned short* __restrict__ w1t,
    const float* __restrict__ b1, const int* __restrict__ ctl, const int* __restrict__ tiles,
    const int* __restrict__ rtok, unsigned short* __restrict__ mid) {
    // flat -> (xcd c, m-tile, n-tile): the 16 n-tiles of one m-tile share c (same XCD L2)
    int flat = blockIdx.x;
    int c8 = flat & 7, q = flat >> 3;
    int nt = q & 15, mt = (q >> 4) * 8 + c8;
    if (mt >= ctl[13]) return;
    int tv = tiles[mt];
    int e = tv >> 16, m0 = tv & 0xFFFF;
    int base = ctl[8 + e];
    int cnt = ctl[9 + e] - base;
    int n0 = nt * 128;

    __shared__ unsigned short smem[2 * BUFE];   // 64 KB dbuf; repack aliases
    __shared__ int toks[128];

    int t = threadIdx.x;
    if (t < 128) {
        int r = m0 + t; if (r >= cnt) r = cnt - 1;
        toks[t] = rtok[base + r];
    }
    __syncthreads();

    const unsigned short* wB = w1t + (size_t)e * HH * DD;
    int w = t >> 6, lane = t & 63;
    int wm = (w & 3) * 32, wn = (w >> 2) * 64;   // wave tile 32x64
    int lrow = lane & 15, quad = lane >> 4;

    const unsigned short* gA[2]; const unsigned short* gB[2];
    unsigned short* lA[2]; unsigned short* lB[2];
    int srow8 = lane >> 3, sch = lane & 7;
#pragma unroll
    for (int cc = 0; cc < 2; cc++) {
        int row = w * 16 + cc * 8 + srow8;
        int cg = (sch - row) & 7;
        gA[cc] = hb + (size_t)toks[row] * DD + cg * 8;
        gB[cc] = wB + (size_t)(n0 + row) * DD + cg * 8;
        lA[cc] = smem + row * BK + sch * 8;
        lB[cc] = smem + 8192 + row * BK + sch * 8;
    }

    floatx4 acc[2][4];
#pragma unroll
    for (int i = 0; i < 2; i++)
#pragma unroll
        for (int j = 0; j < 4; j++) acc[i][j] = (floatx4)0.f;

#pragma unroll
    for (int cc = 0; cc < 2; cc++) { gld_lds16(gA[cc], lA[cc]); gld_lds16(gB[cc], lB[cc]); }
    __syncthreads();

    int bo = 0;
#pragma unroll
    for (int k = 0; k < DD / BK; k++) {
        int nbo = BUFE - bo;
        if (k + 1 < DD / BK) {
            int kk = (k + 1) * BK;
#pragma unroll
            for (int cc = 0; cc < 2; cc++) {
                gld_lds16(gA[cc] + kk, lA[cc] + nbo);
                gld_lds16(gB[cc] + kk, lB[cc] + nbo);
            }
        }
#pragma unroll
        for (int ks = 0; ks < 2; ks++) {
            short8 af[2], bf[4];
#pragma unroll
            for (int i = 0; i < 2; i++) {
                int row = wm + 16 * i + lrow;
                af[i] = *(const short8*)&smem[bo + row * BK + (((ks << 2) + quad + row) & 7) * 8];
            }
#pragma unroll
            for (int j = 0; j < 4; j++) {
                int row = wn + 16 * j + lrow;
                bf[j] = *(const short8*)&smem[bo + 8192 + row * BK + (((ks << 2) + quad + row) & 7) * 8];
            }
#pragma unroll
            for (int i = 0; i < 2; i++)
#pragma unroll
                for (int j = 0; j < 4; j++)
                    acc[i][j] = __builtin_amdgcn_mfma_f32_16x16x32_bf16(af[i], bf[j], acc[i][j], 0, 0, 0);
        }
        __syncthreads();
        bo = nbo;
    }

    // epilogue: bias + relu -> repack (aliases dead staging) -> coalesced stores
    float bias[4];
#pragma unroll
    for (int j = 0; j < 4; j++) bias[j] = b1[e * HH + n0 + wn + 16 * j + lrow];
#pragma unroll
    for (int j = 0; j < 4; j++) {
        int col = wn + 16 * j + lrow;
#pragma unroll
        for (int i = 0; i < 2; i++) {
#pragma unroll
            for (int r = 0; r < 4; r++) {
                int m = wm + 16 * i + quad * 4 + r;
                float v = acc[i][j][r] + bias[j];
                v = v > 0.f ? v : 0.f;
                smem[m * RP + col] = f2bf(v);
            }
        }
    }
    __syncthreads();
    {
        int row = t >> 2, q4 = t & 3;   // 128 rows x 4 chunks of 32 elems
        if (m0 + row < cnt) {
            unsigned short* dst = mid + (size_t)(base + m0 + row) * HH + n0 + q4 * 32;
            const unsigned short* src = smem + row * RP + q4 * 32;
#pragma unroll
            for (int it = 0; it < 4; it++)
                *(uint4*)(dst + it * 8) = *(const uint4*)(src + it * 8);
        }
    }
}

// ---- grouped GEMM 2 (512 thr, 128x128, dbuf, XCD-quartet swizzle): ybuf[slot]=gate*(mid@w2[e]+b2[e]) ----
__global__ __launch_bounds__(512) void k_ffn2(
    const unsigned short* __restrict__ mid, const unsigned short* __restrict__ w2t,
    const float* __restrict__ b2, const int* __restrict__ ctl, const int* __restrict__ tiles,
    const float* __restrict__ rgte, unsigned short* __restrict__ ybuf) {
    // flat -> (xcd c, m-tile, n-tile): the 4 n-tiles of one m-tile share c (same XCD L2 holds mid rows)
    int flat = blockIdx.x;
    int c8 = flat & 7, q = flat >> 3;
    int nt = q & 3, mt = (q >> 2) * 8 + c8;
    if (mt >= ctl[13]) return;
    int tv = tiles[mt];
    int e = tv >> 16, m0 = tv & 0xFFFF;
    int base = ctl[8 + e];
    int cnt = ctl[9 + e] - base;
    int n0 = nt * 128;

    __shared__ unsigned short smem[2 * BUFE];
    __shared__ float gts[128];

    int t = threadIdx.x;
    if (t < 128) {
        int r = m0 + t; if (r >= cnt) r = cnt - 1;
        gts[t] = rgte[base + r];
    }
    __syncthreads();

    const unsigned short* wB = w2t + (size_t)e * DD * HH;
    int w = t >> 6, lane = t & 63;
    int wm = (w & 3) * 32, wn = (w >> 2) * 64;
    int lrow = lane & 15, quad = lane >> 4;

    const unsigned short* gA[2]; const unsigned short* gB[2];
    unsigned short* lA[2]; unsigned short* lB[2];
    int srow8 = lane >> 3, sch = lane & 7;
#pragma unroll
    for (int cc = 0; cc < 2; cc++) {
        int row = w * 16 + cc * 8 + srow8;
        int cg = (sch - row) & 7;
        int ra = m0 + row; if (ra >= cnt) ra = cnt - 1;
        gA[cc] = mid + (size_t)(base + ra) * HH + cg * 8;
        gB[cc] = wB + (size_t)(n0 + row) * HH + cg * 8;
        lA[cc] = smem + row * BK + sch * 8;
        lB[cc] = smem + 8192 + row * BK + sch * 8;
    }

    floatx4 acc[2][4];
#pragma unroll
    for (int i = 0; i < 2; i++)
#pragma unroll
        for (int j = 0; j < 4; j++) acc[i][j] = (floatx4)0.f;

#pragma unroll
    for (int cc = 0; cc < 2; cc++) { gld_lds16(gA[cc], lA[cc]); gld_lds16(gB[cc], lB[cc]); }
    __syncthreads();

    int bo = 0;
    for (int k = 0; k < HH / BK; k++) {
        int nbo = BUFE - bo;
        if (k + 1 < HH / BK) {
            int kk = (k + 1) * BK;
#pragma unroll
            for (int cc = 0; cc < 2; cc++) {
                gld_lds16(gA[cc] + kk, lA[cc] + nbo);
                gld_lds16(gB[cc] + kk, lB[cc] + nbo);
            }
        }
#pragma unroll
        for (int ks = 0; ks < 2; ks++) {
            short8 af[2], bf[4];
#pragma unroll
            for (int i = 0; i < 2; i++) {
                int row = wm + 16 * i + lrow;
                af[i] = *(const short8*)&smem[bo + row * BK + (((ks << 2) + quad + row) & 7) * 8];
            }
#pragma unroll
            for (int j = 0; j < 4; j++) {
                int row = wn + 16 * j + lrow;
                bf[j] = *(const short8*)&smem[bo + 8192 + row * BK + (((ks << 2) + quad + row) & 7) * 8];
            }
#pragma unroll
            for (int i = 0; i < 2; i++)
#pragma unroll
                for (int j = 0; j < 4; j++)
                    acc[i][j] = __builtin_amdgcn_mfma_f32_16x16x32_bf16(af[i], bf[j], acc[i][j], 0, 0, 0);
        }
        __syncthreads();
        bo = nbo;
    }

    // epilogue: bias + gate-scale -> repack -> coalesced stores
    float b2v[4];
#pragma unroll
    for (int j = 0; j < 4; j++) b2v[j] = b2[e * DD + n0 + wn + 16 * j + lrow];
#pragma unroll
    for (int j = 0; j < 4; j++) {
        int col = wn + 16 * j + lrow;
#pragma unroll
        for (int i = 0; i < 2; i++) {
#pragma unroll
            for (int r = 0; r < 4; r++) {
                int m = wm + 16 * i + quad * 4 + r;
                float v = (acc[i][j][r] + b2v[j]) * gts[m];
                smem[m * RP + col] = f2bf(v);
            }
        }
    }
    __syncthreads();
    {
        int row = t >> 2, q4 = t & 3;
        if (m0 + row < cnt) {
            unsigned short* dst = ybuf + (size_t)(base + m0 + row) * DD + n0 + q4 * 32;
            const unsigned short* src = smem + row * RP + q4 * 32;
#pragma unroll
            for (int it = 0; it < 4; it++)
                *(uint4*)(dst + it * 8) = *(const uint4*)(src + it * 8);
        }
    }
}

// ---------------- combine (512 thr, 4 tokens/block): out[n] = ybuf[slot(n,0)] + ybuf[slot(n,1)] ----------------
__global__ __launch_bounds__(512) void k_combine(const unsigned short* __restrict__ ybuf,
                                                 const int* __restrict__ slotof,
                                                 float* __restrict__ out) {
    int n = blockIdx.x * 4 + (threadIdx.x >> 7);
    int c = (threadIdx.x & 127) * 4;
    int sA = slotof[2 * n], sB = slotof[2 * n + 1];
    ushort4 a = *(const ushort4*)(ybuf + (size_t)sA * DD + c);
    ushort4 b = *(const ushort4*)(ybuf + (size_t)sB * DD + c);
    float4 o;
    o.x = bf2f(a.x) + bf2f(b.x);
    o.y = bf2f(a.y) + bf2f(b.y);
    o.z = bf2f(a.z) + bf2f(b.z);
    o.w = bf2f(a.w) + bf2f(b.w);
    *(float4*)(out + (size_t)n * DD + c) = o;
}

extern "C" void kernel_launch(void* const* d_in, const int* in_sizes, int n_in,
                              void* d_out, int out_size, void* d_ws, size_t ws_size,
                              hipStream_t stream) {
    const float* h  = (const float*)d_in[0];
    const float* wg = (const float*)d_in[1];
    const float* w1 = (const float*)d_in[2];
    const float* b1 = (const float*)d_in[3];
    const float* w2 = (const float*)d_in[4];
    const float* b2 = (const float*)d_in[5];
    float* out = (float*)d_out;

    char* ws = (char*)d_ws;
    size_t off = 0;
    auto alloc = [&](size_t bytes) -> void* {
        void* p = ws + off;
        off += (bytes + 255) & ~(size_t)255;
        return p;
    };
    unsigned short* hb  = (unsigned short*)alloc((size_t)NT * DD * 2);        // dead after ffn1
    unsigned short* w1t = (unsigned short*)alloc((size_t)NE * HH * DD * 2);   // dead after ffn1
    unsigned short* w2t = (unsigned short*)alloc((size_t)NE * DD * HH * 2);
    int*   sel    = (int*)alloc((size_t)NT * 2 * 4);
    float* gv     = (float*)alloc((size_t)NT * 2 * 4);
    int*   ctl    = (int*)alloc(256);
    int*   tiles  = (int*)alloc(1024);
    int*   rtok   = (int*)alloc((size_t)NT * 2 * 4);
    float* rgte   = (float*)alloc((size_t)NT * 2 * 4);
    int*   slotof = (int*)alloc((size_t)NT * 2 * 4);
    unsigned short* mid = (unsigned short*)alloc((size_t)NT * 2 * HH * 2);
    // ybuf [NT*2][DD] bf16 (16.7 MB) aliases hb+w1t (16.7 MB), both dead before ffn2 runs
    unsigned short* ybuf = (unsigned short*)ws;

    k_prep<<<dim3(4096 + NT / 8), 512, 0, stream>>>(w1, w1t, w2, w2t, h, wg, sel, gv, hb);
    k_scan<<<1, 1024, 0, stream>>>(sel, gv, ctl, rtok, rgte, slotof, tiles);
    k_ffn1<<<dim3(FFN1_GRID), 512, 0, stream>>>(hb, w1t, b1, ctl, tiles, rtok, mid);
    k_ffn2<<<dim3(FFN2_GRID), 512, 0, stream>>>(mid, w2t, b2, ctl, tiles, rgte, ybuf);
    k_combine<<<dim3(NT / 4), 512, 0, stream>>>(ybuf, slotof, out);
}